// Round 6
// baseline (316.274 us; speedup 1.0000x reference)
//
#include <hip/hip_runtime.h>
#include <hip/hip_bf16.h>

#define Bb 512
#define Ll 64
#define Dd 1024
#define Uu 512

typedef __attribute__((ext_vector_type(8))) short short8;
typedef __attribute__((ext_vector_type(4))) float f32x4;
typedef __attribute__((ext_vector_type(4))) unsigned short u16x4;

__device__ __forceinline__ unsigned short f2bf(float x) {
  unsigned int u = __float_as_uint(x);
  u += 0x7FFF + ((u >> 16) & 1);   // RNE
  return (unsigned short)(u >> 16);
}

// ---------------- k_prep: {h = hidden@W2+b} blocks 0..127; {W1T bf16 [u][k]} blocks 128..383 ----
__global__ void __launch_bounds__(512) k_prep(const float* __restrict__ hidden,
                                              const float* __restrict__ W2w,
                                              const float* __restrict__ W2b,
                                              const float* __restrict__ W1w,
                                              float* __restrict__ h,
                                              unsigned short* __restrict__ W1T) {
  const int t = threadIdx.x;
  if (blockIdx.x < 128) {
    __shared__ float hid[4][Uu];
    const int b0 = blockIdx.x * 4;
#pragma unroll
    for (int i = 0; i < 4; ++i) hid[i][t] = hidden[(size_t)(b0 + i) * Uu + t];
    __syncthreads();
    float a0 = 0.f, a1 = 0.f, a2 = 0.f, a3 = 0.f;
    for (int k0 = 0; k0 < Uu; k0 += 8) {
      float wv[8];
#pragma unroll
      for (int j = 0; j < 8; ++j) wv[j] = W2w[(size_t)(k0 + j) * Uu + t];
#pragma unroll
      for (int j = 0; j < 8; ++j) {
        a0 += hid[0][k0 + j] * wv[j];
        a1 += hid[1][k0 + j] * wv[j];
        a2 += hid[2][k0 + j] * wv[j];
        a3 += hid[3][k0 + j] * wv[j];
      }
    }
    const float bb = W2b[t];
    h[(size_t)(b0 + 0) * Uu + t] = a0 + bb;
    h[(size_t)(b0 + 1) * Uu + t] = a1 + bb;
    h[(size_t)(b0 + 2) * Uu + t] = a2 + bb;
    h[(size_t)(b0 + 3) * Uu + t] = a3 + bb;
  } else {
    const int id = blockIdx.x - 128;  // 0..255
    const int kb = id >> 3;           // 0..31 : 32-k tile
    const int ub = id & 7;            // 0..7  : 64-u tile
    __shared__ float tile[32][68];    // [k][u]
    {
      const int r = t >> 4;           // k 0..31
      const int c4 = t & 15;
      const float4 v = *reinterpret_cast<const float4*>(
          &W1w[(size_t)(kb * 32 + r) * Uu + ub * 64 + c4 * 4]);
      *reinterpret_cast<float4*>(&tile[r][c4 * 4]) = v;
    }
    __syncthreads();
    {
      const int ul = t >> 3;          // u 0..63
      const int ch = t & 7;           // 4-k chunk 0..7
      u16x4 p;
#pragma unroll
      for (int q = 0; q < 4; ++q) p[q] = f2bf(tile[ch * 4 + q][ul]);
      *reinterpret_cast<u16x4*>(&W1T[(size_t)(ub * 64 + ul) * Dd + kb * 32 + ch * 4]) = p;
    }
  }
}

// ---------------- k_fused v4: BK=64, A in LDS (swizzled dbuf), B in registers ----------------
// 1024 threads = 16 waves (wr 0..1 batch-row x wc 0..7 col-block). Wave tile 64x64, acc[4][4].
// A tile: 128 rows x 64 k bf16, row stride 128B, chunk^=(row&7) swizzle -> conflict-free.
// B frags loaded per-lane from W1T (L2-resident, no LDS, no barrier dependency).
__global__ void __launch_bounds__(1024) k_fused(
    const float* __restrict__ features,
    const unsigned short* __restrict__ W1T,
    const float* __restrict__ W1b,
    const float* __restrict__ h,
    const float* __restrict__ Vw,
    const float* __restrict__ Vb,
    float* __restrict__ out_ctx,
    float* __restrict__ out_attn) {
  __shared__ __align__(16) unsigned char smem[32768];  // bufA: 2 x 16384

  const int b0 = blockIdx.x * 2;
  const int tid = threadIdx.x;
  const int lane = tid & 63;
  const int w = tid >> 6;     // 0..15
  const int wr = w >> 3;      // batch row 0..1
  const int wc = w & 7;       // 64-col block
  const int l15 = lane & 15;
  const int lg = (lane >> 4) & 3;

  const float* featB = features + (size_t)b0 * Ll * Dd;

  // A staging: thread -> (row r 0..127, 8-k chunk ch8 0..7)
  const int ar = tid >> 3;
  const int ch8 = tid & 7;
  const float* ag = featB + (size_t)ar * Dd + ch8 * 8;
  const int awoff = ar * 128 + ((ch8 ^ (ar & 7)) << 4);

  // A fragment read offsets: row = wr*64 + mi*16 + l15, chunk = kk*4+lg, swz ^ (l15&7)
  const int e7 = l15 & 7;
  const int sw0 = ((lg ^ e7) << 4);
  const int arow = (wr * 64 + l15) * 128;

  // B fragment base: W1T[(wc*64 + ni*16 + l15)][kt*64 + kk*32 + lg*8]
  const unsigned short* bbase = W1T + (size_t)(wc * 64 + l15) * Dd + lg * 8;

  f32x4 acc[4][4];
#pragma unroll
  for (int mi = 0; mi < 4; ++mi)
#pragma unroll
    for (int ni = 0; ni < 4; ++ni) acc[mi][ni] = (f32x4){0.f, 0.f, 0.f, 0.f};

  // ---- prologue: stage A tile 0 into buf0 ----
  {
    const float4 v0 = *reinterpret_cast<const float4*>(ag);
    const float4 v1 = *reinterpret_cast<const float4*>(ag + 4);
    short8 pa;
    pa[0] = f2bf(v0.x); pa[1] = f2bf(v0.y); pa[2] = f2bf(v0.z); pa[3] = f2bf(v0.w);
    pa[4] = f2bf(v1.x); pa[5] = f2bf(v1.y); pa[6] = f2bf(v1.z); pa[7] = f2bf(v1.w);
    *reinterpret_cast<short8*>(smem + awoff) = pa;
  }
  __syncthreads();

  for (int kt = 0; kt < 16; ++kt) {
    const unsigned char* cA = smem + (kt & 1) * 16384;
    unsigned char* nA = smem + ((kt + 1) & 1) * 16384;
    float4 v0, v1;
    if (kt < 15) {                       // T14: issue next-tile A loads early
      v0 = *reinterpret_cast<const float4*>(ag + (kt + 1) * 64);
      v1 = *reinterpret_cast<const float4*>(ag + (kt + 1) * 64 + 4);
    }
#pragma unroll
    for (int kk = 0; kk < 2; ++kk) {
      const int sw = kk ? (sw0 ^ 64) : sw0;
      short8 afr[4], bfr[4];
#pragma unroll
      for (int mi = 0; mi < 4; ++mi)
        afr[mi] = *reinterpret_cast<const short8*>(cA + arow + mi * 2048 + sw);
#pragma unroll
      for (int ni = 0; ni < 4; ++ni)
        bfr[ni] = *reinterpret_cast<const short8*>(bbase + (size_t)ni * 16 * Dd + kt * 64 + kk * 32);
#pragma unroll
      for (int mi = 0; mi < 4; ++mi)
#pragma unroll
        for (int ni = 0; ni < 4; ++ni)
          acc[mi][ni] = __builtin_amdgcn_mfma_f32_16x16x32_bf16(afr[mi], bfr[ni], acc[mi][ni], 0, 0, 0);
    }
    if (kt < 15) {
      short8 pa;
      pa[0] = f2bf(v0.x); pa[1] = f2bf(v0.y); pa[2] = f2bf(v0.z); pa[3] = f2bf(v0.w);
      pa[4] = f2bf(v1.x); pa[5] = f2bf(v1.y); pa[6] = f2bf(v1.z); pa[7] = f2bf(v1.w);
      *reinterpret_cast<short8*>(nA + awoff) = pa;
    }
    __syncthreads();
  }

  // ---- tanh + V dot ----
  float part[4][4];
#pragma unroll
  for (int mi = 0; mi < 4; ++mi)
#pragma unroll
    for (int r = 0; r < 4; ++r) part[mi][r] = 0.f;

  const int bt = b0 + wr;
#pragma unroll
  for (int ni = 0; ni < 4; ++ni) {
    const int col = wc * 64 + ni * 16 + l15;
    const float hb = h[(size_t)bt * Uu + col];
    const float b1 = W1b[col];
    const float vw = Vw[col];
#pragma unroll
    for (int mi = 0; mi < 4; ++mi)
#pragma unroll
      for (int r = 0; r < 4; ++r) {
        const float x = acc[mi][ni][r] + b1 + hb;
        const float ex = __expf(2.f * x);
        part[mi][r] += vw * (1.f - 2.f / (ex + 1.f));
      }
  }
  float* lpart = (float*)smem;              // [128][8] = 4KB (bufA reuse)
  float* attn_s = (float*)(smem + 4096);    // [128]
#pragma unroll
  for (int mi = 0; mi < 4; ++mi)
#pragma unroll
    for (int r = 0; r < 4; ++r) {
      float v = part[mi][r];
      v += __shfl_xor(v, 1);
      v += __shfl_xor(v, 2);
      v += __shfl_xor(v, 4);
      v += __shfl_xor(v, 8);
      if (l15 == 0) lpart[(wr * 64 + mi * 16 + lg * 4 + r) * 8 + wc] = v;
    }
  __syncthreads();

  // ---- softmax per batch (2 x 64 rows) ----
  if (tid < 128) {
    const int bi = tid >> 6;
    const int row = tid & 63;
    float lgv = Vb[0];
#pragma unroll
    for (int j = 0; j < 8; ++j) lgv += lpart[(bi * 64 + row) * 8 + j];
    float m = lgv;
#pragma unroll
    for (int off = 32; off > 0; off >>= 1) m = fmaxf(m, __shfl_xor(m, off));
    const float ex = __expf(lgv - m);
    float s = ex;
#pragma unroll
    for (int off = 32; off > 0; off >>= 1) s += __shfl_xor(s, off);
    const float a = ex / s;
    attn_s[tid] = a;
    out_attn[(size_t)(b0 + bi) * 64 + row] = a;
  }
  __syncthreads();

  // ---- context: 512 threads per batch, 2 d-columns each (features L2/L3-warm) ----
  {
    const int bi = tid >> 9;
    const int dq = tid & 511;
    const float* fb = features + (size_t)(b0 + bi) * Ll * Dd + dq * 2;
    float2 c2 = {0.f, 0.f};
#pragma unroll 8
    for (int l = 0; l < 64; ++l) {
      const float a = attn_s[bi * 64 + l];
      const float2 f = *reinterpret_cast<const float2*>(fb + (size_t)l * Dd);
      c2.x += a * f.x;
      c2.y += a * f.y;
    }
    *reinterpret_cast<float2*>(&out_ctx[(size_t)(b0 + bi) * Dd + dq * 2]) = c2;
  }
}

extern "C" void kernel_launch(void* const* d_in, const int* in_sizes, int n_in,
                              void* d_out, int out_size, void* d_ws, size_t ws_size,
                              hipStream_t stream) {
  const float* features = (const float*)d_in[0];
  const float* hidden   = (const float*)d_in[1];
  const float* W1w      = (const float*)d_in[2];
  const float* W1b      = (const float*)d_in[3];
  const float* W2w      = (const float*)d_in[4];
  const float* W2b      = (const float*)d_in[5];
  const float* Vw       = (const float*)d_in[6];
  const float* Vb       = (const float*)d_in[7];
  float* out_ctx  = (float*)d_out;                    // [512][1024]
  float* out_attn = (float*)d_out + (size_t)Bb * Dd;  // [512][64]

  float* h = (float*)d_ws;                                        // 1 MB
  unsigned short* W1T = (unsigned short*)((char*)d_ws + (1u << 20));  // 1 MB bf16 [u][k]

  k_prep<<<384, 512, 0, stream>>>(hidden, W2w, W2b, W1w, h, W1T);
  k_fused<<<256, 1024, 0, stream>>>(features, W1T, W1b, h, Vw, Vb, out_ctx, out_attn);
}

// Round 7
// 288.287 us; speedup vs baseline: 1.0971x; 1.0971x over previous
//
#include <hip/hip_runtime.h>
#include <hip/hip_bf16.h>

#define Bb 512
#define Ll 64
#define Dd 1024
#define Uu 512

typedef __attribute__((ext_vector_type(8))) short short8;
typedef __attribute__((ext_vector_type(4))) float f32x4;
typedef __attribute__((ext_vector_type(4))) unsigned short u16x4;

__device__ __forceinline__ unsigned short f2bf(float x) {
  unsigned int u = __float_as_uint(x);
  u += 0x7FFF + ((u >> 16) & 1);   // RNE
  return (unsigned short)(u >> 16);
}

// global_load_lds: per-lane global src, wave-uniform LDS base + lane*16
__device__ __forceinline__ void gld16(const void* g, void* l) {
  auto gp = reinterpret_cast<const __attribute__((address_space(1))) unsigned int*>(
      reinterpret_cast<uintptr_t>(g));
  auto lp = reinterpret_cast<__attribute__((address_space(3))) unsigned int*>(
      reinterpret_cast<uintptr_t>(l));
  __builtin_amdgcn_global_load_lds(gp, lp, 16, 0, 0);
}

// ---------------- k_prep: {h = hidden@W2+b} blocks 0..127; {W1s image} blocks 128..383 ----
// W1s image (per 32-k tile kb): byte = u*64 + ((ch ^ ((u>>1)&3))<<4) + j*2, ch=(k&31)>>3, j=k&7.
// The (u>>1)&3 swizzle spreads 16 consecutive u-rows over all 8 16B-slots per 128B bank
// cycle -> 2-way (free) on the fused kernel's B-frag ds_read_b128.
__global__ void __launch_bounds__(512) k_prep(const float* __restrict__ hidden,
                                              const float* __restrict__ W2w,
                                              const float* __restrict__ W2b,
                                              const float* __restrict__ W1w,
                                              float* __restrict__ h,
                                              unsigned char* __restrict__ W1s) {
  const int t = threadIdx.x;
  if (blockIdx.x < 128) {
    __shared__ float hid[4][Uu];
    const int b0 = blockIdx.x * 4;
#pragma unroll
    for (int i = 0; i < 4; ++i) hid[i][t] = hidden[(size_t)(b0 + i) * Uu + t];
    __syncthreads();
    float a0 = 0.f, a1 = 0.f, a2 = 0.f, a3 = 0.f;
    for (int k0 = 0; k0 < Uu; k0 += 8) {
      float wv[8];
#pragma unroll
      for (int j = 0; j < 8; ++j) wv[j] = W2w[(size_t)(k0 + j) * Uu + t];
#pragma unroll
      for (int j = 0; j < 8; ++j) {
        a0 += hid[0][k0 + j] * wv[j];
        a1 += hid[1][k0 + j] * wv[j];
        a2 += hid[2][k0 + j] * wv[j];
        a3 += hid[3][k0 + j] * wv[j];
      }
    }
    const float bb = W2b[t];
    h[(size_t)(b0 + 0) * Uu + t] = a0 + bb;
    h[(size_t)(b0 + 1) * Uu + t] = a1 + bb;
    h[(size_t)(b0 + 2) * Uu + t] = a2 + bb;
    h[(size_t)(b0 + 3) * Uu + t] = a3 + bb;
  } else {
    const int id = blockIdx.x - 128;  // 0..255
    const int kb = id >> 3;           // 0..31 : 32-k tile
    const int ub = id & 7;            // 0..7  : 64-u tile
    __shared__ float tile[32][68];    // [k][u]
    {
      const int r = t >> 4;
      const int c4 = t & 15;
      const float4 v = *reinterpret_cast<const float4*>(
          &W1w[(size_t)(kb * 32 + r) * Uu + ub * 64 + c4 * 4]);
      *reinterpret_cast<float4*>(&tile[r][c4 * 4]) = v;
    }
    __syncthreads();
    if (t < 256) {
      const int ul = t >> 2;          // 0..63
      const int ch = t & 3;           // 16B chunk (8 k)
      const int u = ub * 64 + ul;
      unsigned int px[4];
#pragma unroll
      for (int q = 0; q < 4; ++q) {
        const unsigned int lo = f2bf(tile[ch * 8 + q * 2][ul]);
        const unsigned int hi = f2bf(tile[ch * 8 + q * 2 + 1][ul]);
        px[q] = lo | (hi << 16);
      }
      const int sw = ch ^ ((ul >> 1) & 3);  // (u>>1)&3 == (ul>>1)&3 (ub*64 is mult of 8)
      uint4 pack;
      pack.x = px[0]; pack.y = px[1]; pack.z = px[2]; pack.w = px[3];
      *reinterpret_cast<uint4*>(&W1s[(size_t)kb * 32768 + u * 64 + sw * 16]) = pack;
    }
  }
}

// ---------------- k_fused v5: R5 structure, conflict-free swizzles, setprio --------------
// 1024 thr = 16 waves (wr 0..1 x wc 0..7). Wave tile 64x64, acc[4][4]. BK=32, 32 K-steps.
// A: 128 rows x 64B, dbuf, reg-staged f32->bf16, slot = (ap>>1)^((row>>1)&3) -> 2-way free.
// B: 512 rows x 64B, dbuf, async global_load_lds from pre-swizzled W1s (linear copy).
__global__ void __launch_bounds__(1024) k_fused(
    const float* __restrict__ features,
    const unsigned char* __restrict__ W1s,
    const float* __restrict__ W1b,
    const float* __restrict__ h,
    const float* __restrict__ Vw,
    const float* __restrict__ Vb,
    float* __restrict__ out_attn) {
  __shared__ __align__(16) unsigned char smem[81920];
  unsigned char* bufA = smem;           // 2 x 8192
  unsigned char* bufB = smem + 16384;   // 2 x 32768

  const int b0 = blockIdx.x * 2;
  const int tid = threadIdx.x;
  const int lane = tid & 63;
  const int w = tid >> 6;     // 0..15
  const int wr = w >> 3;      // batch row 0..1
  const int wc = w & 7;       // 64-col block
  const int l15 = lane & 15;
  const int lg = (lane >> 4) & 3;

  const float* featB = features + (size_t)b0 * Ll * Dd;

  // A staging: thread -> (row ar 0..127, float4 chunk ap 0..7 of the 32-k window)
  const int ar = tid >> 3;
  const int ap = tid & 7;
  const float* ag = featB + (size_t)ar * Dd + ap * 4;
  const int awoff = ar * 64 + (((ap >> 1) ^ ((ar >> 1) & 3)) << 4) + (ap & 1) * 8;

  // fragment read offsets: slot = lg ^ ((row>>1)&3); row>>1&3 == l15>>1&3 for both A and B
  const int swl = (lg ^ ((l15 >> 1) & 3)) << 4;
  const int aoff0 = (wr * 64 + l15) * 64 + swl;        // + mi*1024
  const int boff0 = (wc * 64 + l15) * 64 + swl;        // + ni*1024

  f32x4 acc[4][4];
#pragma unroll
  for (int mi = 0; mi < 4; ++mi)
#pragma unroll
    for (int ni = 0; ni < 4; ++ni) acc[mi][ni] = (f32x4){0.f, 0.f, 0.f, 0.f};

  // ---- prologue: stage kt=0 into buffer 0 ----
  {
    const float4 va = *reinterpret_cast<const float4*>(ag);
    const unsigned char* src = W1s + (size_t)(w * 2) * 1024 + lane * 16;
    unsigned char* dst = bufB + (w * 2) * 1024;
    gld16(src, dst);
    gld16(src + 1024, dst + 1024);
    u16x4 pa = {f2bf(va.x), f2bf(va.y), f2bf(va.z), f2bf(va.w)};
    *reinterpret_cast<u16x4*>(bufA + awoff) = pa;
  }
  __syncthreads();

  for (int kt = 0; kt < 32; ++kt) {
    const int cur = kt & 1;
    const unsigned char* cA = bufA + cur * 8192;
    const unsigned char* cB = bufB + cur * 32768;
    float4 va;
    if (kt < 31) {
      va = *reinterpret_cast<const float4*>(ag + (kt + 1) * 32);        // A prefetch (reg)
      const unsigned char* src = W1s + (size_t)(kt + 1) * 32768 + (w * 2) * 1024 + lane * 16;
      unsigned char* dst = bufB + (cur ^ 1) * 32768 + (w * 2) * 1024;
      gld16(src, dst);                                                  // B prefetch (DMA)
      gld16(src + 1024, dst + 1024);
    }
    short8 afr[4], bfr[4];
#pragma unroll
    for (int mi = 0; mi < 4; ++mi)
      afr[mi] = *reinterpret_cast<const short8*>(cA + aoff0 + mi * 1024);
#pragma unroll
    for (int ni = 0; ni < 4; ++ni)
      bfr[ni] = *reinterpret_cast<const short8*>(cB + boff0 + ni * 1024);
    __builtin_amdgcn_s_setprio(1);
#pragma unroll
    for (int mi = 0; mi < 4; ++mi)
#pragma unroll
      for (int ni = 0; ni < 4; ++ni)
        acc[mi][ni] = __builtin_amdgcn_mfma_f32_16x16x32_bf16(afr[mi], bfr[ni], acc[mi][ni], 0, 0, 0);
    __builtin_amdgcn_s_setprio(0);
    if (kt < 31) {
      u16x4 pa = {f2bf(va.x), f2bf(va.y), f2bf(va.z), f2bf(va.w)};
      *reinterpret_cast<u16x4*>(bufA + (cur ^ 1) * 8192 + awoff) = pa;
    }
    __syncthreads();
  }

  // ---- tanh + V dot ----
  float part[4][4];
#pragma unroll
  for (int mi = 0; mi < 4; ++mi)
#pragma unroll
    for (int r = 0; r < 4; ++r) part[mi][r] = 0.f;

  const int bt = b0 + wr;
#pragma unroll
  for (int ni = 0; ni < 4; ++ni) {
    const int col = wc * 64 + ni * 16 + l15;
    const float hb = h[(size_t)bt * Uu + col];
    const float b1 = W1b[col];
    const float vw = Vw[col];
#pragma unroll
    for (int mi = 0; mi < 4; ++mi)
#pragma unroll
      for (int r = 0; r < 4; ++r) {
        const float x = acc[mi][ni][r] + b1 + hb;
        const float e = __expf(2.f * x);
        part[mi][r] += vw * (1.f - 2.f / (e + 1.f));
      }
  }
  float* lpart = (float*)smem;  // [128][8]
#pragma unroll
  for (int mi = 0; mi < 4; ++mi)
#pragma unroll
    for (int r = 0; r < 4; ++r) {
      float v = part[mi][r];
      v += __shfl_xor(v, 1);
      v += __shfl_xor(v, 2);
      v += __shfl_xor(v, 4);
      v += __shfl_xor(v, 8);
      if (l15 == 0) lpart[(wr * 64 + mi * 16 + lg * 4 + r) * 8 + wc] = v;
    }
  __syncthreads();

  if (tid < 128) {
    const int bi = tid >> 6;
    const int row = tid & 63;
    float lgv = Vb[0];
#pragma unroll
    for (int j = 0; j < 8; ++j) lgv += lpart[(bi * 64 + row) * 8 + j];
    float m = lgv;
#pragma unroll
    for (int off = 32; off > 0; off >>= 1) m = fmaxf(m, __shfl_xor(m, off));
    const float e = __expf(lgv - m);
    float s = e;
#pragma unroll
    for (int off = 32; off > 0; off >>= 1) s += __shfl_xor(s, off);
    out_attn[(size_t)(b0 + bi) * 64 + row] = e / s;
  }
}

// ---------------- k_ctx: context = attn^T @ features, one block per batch --------------
__global__ void __launch_bounds__(256) k_ctx(const float* __restrict__ features,
                                             const float* __restrict__ attn,
                                             float* __restrict__ out_ctx) {
  __shared__ float a_s[64];
  const int b = blockIdx.x;
  const int t = threadIdx.x;
  if (t < 64) a_s[t] = attn[(size_t)b * 64 + t];
  __syncthreads();
  const float* fb = features + (size_t)b * Ll * Dd + t * 4;
  float4 acc = {0.f, 0.f, 0.f, 0.f};
#pragma unroll 8
  for (int l = 0; l < 64; ++l) {
    const float4 f = *reinterpret_cast<const float4*>(fb + (size_t)l * Dd);
    const float a = a_s[l];
    acc.x += a * f.x;
    acc.y += a * f.y;
    acc.z += a * f.z;
    acc.w += a * f.w;
  }
  *reinterpret_cast<float4*>(out_ctx + (size_t)b * Dd + t * 4) = acc;
}

extern "C" void kernel_launch(void* const* d_in, const int* in_sizes, int n_in,
                              void* d_out, int out_size, void* d_ws, size_t ws_size,
                              hipStream_t stream) {
  const float* features = (const float*)d_in[0];
  const float* hidden   = (const float*)d_in[1];
  const float* W1w      = (const float*)d_in[2];
  const float* W1b      = (const float*)d_in[3];
  const float* W2w      = (const float*)d_in[4];
  const float* W2b      = (const float*)d_in[5];
  const float* Vw       = (const float*)d_in[6];
  const float* Vb       = (const float*)d_in[7];
  float* out_ctx  = (float*)d_out;                    // [512][1024]
  float* out_attn = (float*)d_out + (size_t)Bb * Dd;  // [512][64]

  float* h = (float*)d_ws;                                  // 1 MB
  unsigned char* W1s = (unsigned char*)d_ws + (1u << 20);   // 1 MB swizzled bf16 image

  k_prep<<<384, 512, 0, stream>>>(hidden, W2w, W2b, W1w, h, W1s);
  k_fused<<<256, 1024, 0, stream>>>(features, W1s, W1b, h, Vw, Vb, out_attn);
  k_ctx<<<Bb, 256, 0, stream>>>(features, out_attn, out_ctx);
}